// Round 1
// baseline (1953.179 us; speedup 1.0000x reference)
//
#include <hip/hip_runtime.h>
#include <hip/hip_bf16.h>
#include <stdint.h>

// Autoformer AutoCorrelation block, MI355X (gfx950).
// Pipeline: Q/K proj (split-bf16 3-pass MFMA, fp32-accurate) -> Gram diag-reduce
// (split-bf16, atomic mean_value) -> top7+softmax -> weighted circular gather ->
// output proj (1-pass bf16 MFMA).

typedef float  f32x4 __attribute__((ext_vector_type(4)));
typedef __bf16 bf16x8 __attribute__((ext_vector_type(8)));
typedef unsigned short u16x4 __attribute__((ext_vector_type(4)));
typedef unsigned short u16x8 __attribute__((ext_vector_type(8)));

#define EPI_F32  0
#define EPI_BF16 1
#define EPI_DIAG 2

__device__ inline float bf2f(unsigned short h) {
    unsigned int u = ((unsigned int)h) << 16;
    float f; __builtin_memcpy(&f, &u, 4); return f;
}
__device__ inline unsigned short f2bf(float f) {
    unsigned int u; __builtin_memcpy(&u, &f, 4);
    u += 0x7fffu + ((u >> 16) & 1u);   // RN-even; inputs are finite
    return (unsigned short)(u >> 16);
}

// C[i,j] = sum_d A[i,d]*B[j,d] (+bias[j]); both operands K-contiguous (A@W^T form).
// Tile 128x128, BK=64, 256 threads = 4 waves (2x2), each wave 64x64 via 4x4
// mfma_f32_16x16x32_bf16 frags. LDS XOR-swizzle (row&7)<<4 on byte addr (T2).
// SPLIT=1: A,B staged as bf16 hi+lo; 3 MFMA per frag pair -> ~fp32 precision.
// ABF=1: A operand source is bf16 (Vagg) instead of fp32.
template<int SPLIT, int ABF, int EPI>
__global__ __launch_bounds__(256, 2) void gemm_k(
    const void* __restrict__ Ap, const float* __restrict__ Bp,
    const float* __restrict__ bias, void* __restrict__ Cp,
    int K, int lda, int ldb, int ldc,
    long aBatch, long bBatch, long cBatch)
{
    __shared__ __align__(16) char smem[(SPLIT ? 4 : 2) * 16384];
    char* sAhi = smem;
    char* sAlo = smem + 16384;
    char* sBhi = smem + (SPLIT ? 32768 : 16384);
    char* sBlo = smem + 49152;

    const int tid = threadIdx.x;
    const int bx = blockIdx.x, by = blockIdx.y, bz = blockIdx.z;
    const int lane = tid & 63, wid = tid >> 6;
    const int wm = wid >> 1, wn = wid & 1;            // 2x2 wave grid
    const int lrow = lane & 15;                        // frag row/col within 16
    const int lkb  = (lane >> 4) << 3;                 // k sub-offset 0/8/16/24

    const float*          A32 = (const float*)Ap + (size_t)bz * aBatch;
    const unsigned short* A16 = (const unsigned short*)Ap + (size_t)bz * aBatch;
    const float*          B32 = Bp + (size_t)bz * bBatch;

    f32x4 acc[4][4];
#pragma unroll
    for (int m = 0; m < 4; ++m)
#pragma unroll
        for (int n = 0; n < 4; ++n) acc[m][n] = (f32x4)(0.0f);

    for (int k0 = 0; k0 < K; k0 += 64) {
        // ---- stage A tile (128 rows x 64 k) ----
        if constexpr (!ABF) {
#pragma unroll
            for (int p = 0; p < 8; ++p) {
                int gi = (p << 8) + tid;
                int r = gi >> 4, g4 = gi & 15;         // 16 float4-granules per row
                const float* s = A32 + (size_t)(by * 128 + r) * lda + (k0 + (g4 << 2));
                f32x4 v = *(const f32x4*)s;
                u16x4 h, l;
#pragma unroll
                for (int j = 0; j < 4; ++j) {
                    unsigned short hb = f2bf(v[j]);
                    h[j] = hb;
                    if constexpr (SPLIT) l[j] = f2bf(v[j] - bf2f(hb));
                }
                int x = (g4 << 3) ^ ((r & 7) << 4);    // XOR-swizzled byte within 128B row
                *(u16x4*)(sAhi + (r << 7) + x) = h;
                if constexpr (SPLIT) *(u16x4*)(sAlo + (r << 7) + x) = l;
            }
        } else {
#pragma unroll
            for (int p = 0; p < 4; ++p) {
                int gi = (p << 8) + tid;
                int r = gi >> 3, g8 = gi & 7;          // 8 x 16B granules per row
                const unsigned short* s = A16 + (size_t)(by * 128 + r) * lda + (k0 + (g8 << 3));
                u16x8 v = *(const u16x8*)s;
                int x = (g8 << 4) ^ ((r & 7) << 4);
                *(u16x8*)(sAhi + (r << 7) + x) = v;
            }
        }
        // ---- stage B tile (always fp32 source) ----
#pragma unroll
        for (int p = 0; p < 8; ++p) {
            int gi = (p << 8) + tid;
            int r = gi >> 4, g4 = gi & 15;
            const float* s = B32 + (size_t)(bx * 128 + r) * ldb + (k0 + (g4 << 2));
            f32x4 v = *(const f32x4*)s;
            u16x4 h, l;
#pragma unroll
            for (int j = 0; j < 4; ++j) {
                unsigned short hb = f2bf(v[j]);
                h[j] = hb;
                if constexpr (SPLIT) l[j] = f2bf(v[j] - bf2f(hb));
            }
            int x = (g4 << 3) ^ ((r & 7) << 4);
            *(u16x4*)(sBhi + (r << 7) + x) = h;
            if constexpr (SPLIT) *(u16x4*)(sBlo + (r << 7) + x) = l;
        }
        __syncthreads();

#pragma unroll
        for (int kk = 0; kk < 64; kk += 32) {
            bf16x8 ah[4], al[4], bh[4], bl[4];
#pragma unroll
            for (int m = 0; m < 4; ++m) {
                int row = wm * 64 + m * 16 + lrow;
                int off = (row << 7) + ((((kk + lkb) << 1)) ^ ((row & 7) << 4));
                ah[m] = *(const bf16x8*)(sAhi + off);
                if constexpr (SPLIT) al[m] = *(const bf16x8*)(sAlo + off);
            }
#pragma unroll
            for (int n = 0; n < 4; ++n) {
                int row = wn * 64 + n * 16 + lrow;
                int off = (row << 7) + ((((kk + lkb) << 1)) ^ ((row & 7) << 4));
                bh[n] = *(const bf16x8*)(sBhi + off);
                if constexpr (SPLIT) bl[n] = *(const bf16x8*)(sBlo + off);
            }
#pragma unroll
            for (int m = 0; m < 4; ++m)
#pragma unroll
                for (int n = 0; n < 4; ++n) {
                    acc[m][n] = __builtin_amdgcn_mfma_f32_16x16x32_bf16(ah[m], bh[n], acc[m][n], 0, 0, 0);
                    if constexpr (SPLIT) {
                        acc[m][n] = __builtin_amdgcn_mfma_f32_16x16x32_bf16(al[m], bh[n], acc[m][n], 0, 0, 0);
                        acc[m][n] = __builtin_amdgcn_mfma_f32_16x16x32_bf16(ah[m], bl[n], acc[m][n], 0, 0, 0);
                    }
                }
        }
        __syncthreads();
    }

    const int r4 = (lane >> 4) << 2;   // C/D: col=lane&15, row=(lane>>4)*4+reg (m89)
    if constexpr (EPI == EPI_DIAG) {
        // Reduce tile into circular diagonals tau = (i - j) mod 2048, scaled 1/1024.
        float* bins = (float*)smem;    // safe: k-loop ended with __syncthreads()
        if (tid < 255) bins[tid] = 0.0f;
        __syncthreads();
#pragma unroll
        for (int m = 0; m < 4; ++m)
#pragma unroll
            for (int n = 0; n < 4; ++n) {
                int colr = wn * 64 + n * 16 + lrow;
#pragma unroll
                for (int rr = 0; rr < 4; ++rr) {
                    int d = (wm * 64 + m * 16 + r4 + rr) - colr + 127;
                    atomicAdd(&bins[d], acc[m][n][rr]);
                }
            }
        __syncthreads();
        if (tid < 255) {
            float* mv = (float*)Cp + (size_t)bz * cBatch;
            int tau = ((by - bx) * 128 + tid - 127) & 2047;
            atomicAdd(&mv[tau], bins[tid] * (1.0f / 1024.0f));
        }
    } else {
#pragma unroll
        for (int n = 0; n < 4; ++n) {
            int colg = bx * 128 + wn * 64 + n * 16 + lrow;
            float bv = bias[colg];
#pragma unroll
            for (int m = 0; m < 4; ++m)
#pragma unroll
                for (int rr = 0; rr < 4; ++rr) {
                    int rowg = by * 128 + wm * 64 + m * 16 + r4 + rr;
                    float v = acc[m][n][rr] + bv;
                    if constexpr (EPI == EPI_F32)
                        ((float*)Cp)[(size_t)rowg * ldc + colg] = v;
                    else
                        ((unsigned short*)Cp)[(size_t)rowg * ldc + colg] = f2bf(v);
                }
        }
    }
}

// Stable top-7 (lax.top_k semantics: descending, ties -> lowest index) + softmax.
__global__ __launch_bounds__(256) void topk_k(const float* __restrict__ mv,
                                              float* __restrict__ wts,
                                              int* __restrict__ dly)
{
    const int b = blockIdx.x, t = threadIdx.x;
    __shared__ float v[2048];
    __shared__ float rv[256];
    __shared__ int   ri[256];
    __shared__ float topv[7];
    __shared__ int   topi[7];
    for (int i = t; i < 2048; i += 256) v[i] = mv[b * 2048 + i];
    __syncthreads();
    for (int k = 0; k < 7; ++k) {
        float bvv = -INFINITY; int bii = 0x7fffffff;
        for (int i = t; i < 2048; i += 256) {
            float x = v[i];
            if (x > bvv) { bvv = x; bii = i; }   // strict > keeps lowest index
        }
        rv[t] = bvv; ri[t] = bii;
        __syncthreads();
        for (int s = 128; s > 0; s >>= 1) {
            if (t < s) {
                float ov = rv[t + s]; int oi = ri[t + s];
                if (ov > rv[t] || (ov == rv[t] && oi < ri[t])) { rv[t] = ov; ri[t] = oi; }
            }
            __syncthreads();
        }
        if (t == 0) { topv[k] = rv[0]; topi[k] = ri[0]; v[ri[0]] = -INFINITY; }
        __syncthreads();
    }
    if (t == 0) {
        float mx = topv[0], e[7], s = 0.0f;
        for (int k = 0; k < 7; ++k) { e[k] = expf(topv[k] - mx); s += e[k]; }
        for (int k = 0; k < 7; ++k) { wts[b * 7 + k] = e[k] / s; dly[b * 7 + k] = topi[k]; }
    }
}

// V_agg[b,t,:] = sum_k w_k * V[b,(t+d_k)%2048,:]  (bf16 in/out, 8 elems/thread)
__global__ __launch_bounds__(256) void gather_k(const unsigned short* __restrict__ V,
                                                const float* __restrict__ wts,
                                                const int* __restrict__ dly,
                                                unsigned short* __restrict__ Vagg)
{
    int idx = blockIdx.x * 256 + threadIdx.x;   // chunk of 8 bf16
    int c   = (idx & 127) << 3;
    int row = idx >> 7;                          // b*2048 + t
    int b = row >> 11, t = row & 2047;
    float acc[8] = {0.f, 0.f, 0.f, 0.f, 0.f, 0.f, 0.f, 0.f};
    for (int k = 0; k < 7; ++k) {
        float w = wts[b * 7 + k];
        int   d = dly[b * 7 + k];
        const unsigned short* s = V + (((size_t)((b << 11) + ((t + d) & 2047))) << 10) + c;
        u16x8 x = *(const u16x8*)s;
#pragma unroll
        for (int j = 0; j < 8; ++j) acc[j] += w * bf2f(x[j]);
    }
    u16x8 o;
#pragma unroll
    for (int j = 0; j < 8; ++j) o[j] = f2bf(acc[j]);
    *(u16x8*)(Vagg + (((size_t)row) << 10) + c) = o;
}

extern "C" void kernel_launch(void* const* d_in, const int* in_sizes, int n_in,
                              void* d_out, int out_size, void* d_ws, size_t ws_size,
                              hipStream_t stream) {
    const float* q_in = (const float*)d_in[0];
    const float* k_in = (const float*)d_in[1];
    const float* v_in = (const float*)d_in[2];
    const float* Wq   = (const float*)d_in[3];
    const float* bq   = (const float*)d_in[4];
    const float* Wk   = (const float*)d_in[5];
    const float* bk   = (const float*)d_in[6];
    const float* Wv   = (const float*)d_in[7];
    const float* bv   = (const float*)d_in[8];
    const float* Wo   = (const float*)d_in[9];
    const float* bo   = (const float*)d_in[10];

    // Q (fp32, 64 MiB) lives in d_out: dead before the final GEMM overwrites it.
    float* Q  = (float*)d_out;
    char*  ws = (char*)d_ws;
    float*          Kf   = (float*)(ws);                        // 67108864 B
    unsigned short* Vbf  = (unsigned short*)(ws + 67108864);    // 33554432 B
    unsigned short* Vagg = (unsigned short*)(ws + 100663296);   // 33554432 B
    float*          mv   = (float*)(ws + 134217728);            // 65536 B
    float*          wts  = (float*)(ws + 134283264);
    int*            dly  = (int*)(ws + 134283520);

    hipMemsetAsync(mv, 0, 8 * 2048 * sizeof(float), stream);

    dim3 blk(256, 1, 1);
    dim3 gproj(8, 128, 1);   // N/128=8, M/128=128

    // Q = q_in @ Wq^T + bq   (split-3, fp32 out)
    gemm_k<1, 0, EPI_F32><<<gproj, blk, 0, stream>>>(q_in, Wq, bq, Q,
        1024, 1024, 1024, 1024, 0, 0, 0);
    // K = k_in @ Wk^T + bk
    gemm_k<1, 0, EPI_F32><<<gproj, blk, 0, stream>>>(k_in, Wk, bk, Kf,
        1024, 1024, 1024, 1024, 0, 0, 0);
    // V = v_in @ Wv^T + bv   (1-pass, bf16 out)
    gemm_k<0, 0, EPI_BF16><<<gproj, blk, 0, stream>>>(v_in, Wv, bv, Vbf,
        1024, 1024, 1024, 1024, 0, 0, 0);
    // mean_value[b,tau] += diag-sums of Q_b K_b^T / 1024   (split-3)
    gemm_k<1, 0, EPI_DIAG><<<dim3(16, 16, 8), blk, 0, stream>>>(Q, Kf, nullptr, mv,
        1024, 1024, 1024, 0, 2048L * 1024, 2048L * 1024, 2048);
    // top-7 + softmax
    topk_k<<<dim3(8, 1, 1), blk, 0, stream>>>(mv, wts, dly);
    // weighted circular gather
    gather_k<<<dim3(8192, 1, 1), blk, 0, stream>>>(Vbf, wts, dly, Vagg);
    // out = V_agg @ Wo^T + bo   (1-pass, A is bf16, fp32 out -> overwrites Q)
    gemm_k<0, 1, EPI_F32><<<gproj, blk, 0, stream>>>(Vagg, Wo, bo, (float*)d_out,
        1024, 1024, 1024, 1024, 0, 0, 0);
}

// Round 12
// 1367.865 us; speedup vs baseline: 1.4279x; 1.4279x over previous
//
#include <hip/hip_runtime.h>
#include <hip/hip_bf16.h>
#include <stdint.h>

// Autoformer AutoCorrelation block, MI355X (gfx950).
// Round 2 design (10th resubmit; ten GPU-acquisition timeouts in a row):
// replace Gram diag-reduce GEMM (748us) with FFT autocorrelation:
//   Q/K proj (split-bf16 3-pass MFMA) write TRANSPOSED fp32 [b][c][t]
//   -> per-channel complex FFT (q + i*k packed), Hermitian unpack,
//      accumulate S[b,f] = sum_c Qhat*conj(Khat)
//   -> inverse FFT -> mean_value -> top7+softmax -> weighted circular gather
//   -> output proj (1-pass bf16 MFMA).

typedef float  f32x4 __attribute__((ext_vector_type(4)));
typedef __bf16 bf16x8 __attribute__((ext_vector_type(8)));
typedef unsigned short u16x4 __attribute__((ext_vector_type(4)));
typedef unsigned short u16x8 __attribute__((ext_vector_type(8)));

#define EPI_F32  0
#define EPI_BF16 1
#define EPI_F32T 2   // store transposed: C[b][col][t]  (t = row within batch)

__device__ inline float bf2f(unsigned short h) {
    unsigned int u = ((unsigned int)h) << 16;
    float f; __builtin_memcpy(&f, &u, 4); return f;
}
__device__ inline unsigned short f2bf(float f) {
    unsigned int u; __builtin_memcpy(&u, &f, 4);
    u += 0x7fffu + ((u >> 16) & 1u);   // RN-even; inputs are finite
    return (unsigned short)(u >> 16);
}

// C[i,j] = sum_d A[i,d]*B[j,d] (+bias[j]); both operands K-contiguous (A@W^T).
// Tile 128x128, BK=64, 4 waves (2x2), mfma_f32_16x16x32_bf16, LDS XOR-swizzle.
// SPLIT=1: A,B staged as bf16 hi+lo; 3 MFMA per frag pair -> ~fp32 precision.
// ABF=1: A operand source is bf16 (Vagg) instead of fp32.
template<int SPLIT, int ABF, int EPI>
__global__ __launch_bounds__(256, 2) void gemm_k(
    const void* __restrict__ Ap, const float* __restrict__ Bp,
    const float* __restrict__ bias, void* __restrict__ Cp,
    int K, int lda, int ldb, int ldc)
{
    __shared__ __align__(16) char smem[(SPLIT ? 4 : 2) * 16384];
    char* sAhi = smem;
    char* sAlo = smem + 16384;
    char* sBhi = smem + (SPLIT ? 32768 : 16384);
    char* sBlo = smem + 49152;

    const int tid = threadIdx.x;
    const int bx = blockIdx.x, by = blockIdx.y;
    const int lane = tid & 63, wid = tid >> 6;
    const int wm = wid >> 1, wn = wid & 1;
    const int lrow = lane & 15;
    const int lkb  = (lane >> 4) << 3;

    const float*          A32 = (const float*)Ap;
    const unsigned short* A16 = (const unsigned short*)Ap;
    const float*          B32 = Bp;

    f32x4 acc[4][4];
#pragma unroll
    for (int m = 0; m < 4; ++m)
#pragma unroll
        for (int n = 0; n < 4; ++n) acc[m][n] = (f32x4)(0.0f);

    for (int k0 = 0; k0 < K; k0 += 64) {
        if constexpr (!ABF) {
#pragma unroll
            for (int p = 0; p < 8; ++p) {
                int gi = (p << 8) + tid;
                int r = gi >> 4, g4 = gi & 15;
                const float* s = A32 + (size_t)(by * 128 + r) * lda + (k0 + (g4 << 2));
                f32x4 v = *(const f32x4*)s;
                u16x4 h, l;
#pragma unroll
                for (int j = 0; j < 4; ++j) {
                    unsigned short hb = f2bf(v[j]);
                    h[j] = hb;
                    if constexpr (SPLIT) l[j] = f2bf(v[j] - bf2f(hb));
                }
                int x = (g4 << 3) ^ ((r & 7) << 4);
                *(u16x4*)(sAhi + (r << 7) + x) = h;
                if constexpr (SPLIT) *(u16x4*)(sAlo + (r << 7) + x) = l;
            }
        } else {
#pragma unroll
            for (int p = 0; p < 4; ++p) {
                int gi = (p << 8) + tid;
                int r = gi >> 3, g8 = gi & 7;
                const unsigned short* s = A16 + (size_t)(by * 128 + r) * lda + (k0 + (g8 << 3));
                u16x8 v = *(const u16x8*)s;
                int x = (g8 << 4) ^ ((r & 7) << 4);
                *(u16x8*)(sAhi + (r << 7) + x) = v;
            }
        }
#pragma unroll
        for (int p = 0; p < 8; ++p) {
            int gi = (p << 8) + tid;
            int r = gi >> 4, g4 = gi & 15;
            const float* s = B32 + (size_t)(bx * 128 + r) * ldb + (k0 + (g4 << 2));
            f32x4 v = *(const f32x4*)s;
            u16x4 h, l;
#pragma unroll
            for (int j = 0; j < 4; ++j) {
                unsigned short hb = f2bf(v[j]);
                h[j] = hb;
                if constexpr (SPLIT) l[j] = f2bf(v[j] - bf2f(hb));
            }
            int x = (g4 << 3) ^ ((r & 7) << 4);
            *(u16x4*)(sBhi + (r << 7) + x) = h;
            if constexpr (SPLIT) *(u16x4*)(sBlo + (r << 7) + x) = l;
        }
        __syncthreads();

#pragma unroll
        for (int kk = 0; kk < 64; kk += 32) {
            bf16x8 ah[4], al[4], bh[4], bl[4];
#pragma unroll
            for (int m = 0; m < 4; ++m) {
                int row = wm * 64 + m * 16 + lrow;
                int off = (row << 7) + ((((kk + lkb) << 1)) ^ ((row & 7) << 4));
                ah[m] = *(const bf16x8*)(sAhi + off);
                if constexpr (SPLIT) al[m] = *(const bf16x8*)(sAlo + off);
            }
#pragma unroll
            for (int n = 0; n < 4; ++n) {
                int row = wn * 64 + n * 16 + lrow;
                int off = (row << 7) + ((((kk + lkb) << 1)) ^ ((row & 7) << 4));
                bh[n] = *(const bf16x8*)(sBhi + off);
                if constexpr (SPLIT) bl[n] = *(const bf16x8*)(sBlo + off);
            }
#pragma unroll
            for (int m = 0; m < 4; ++m)
#pragma unroll
                for (int n = 0; n < 4; ++n) {
                    acc[m][n] = __builtin_amdgcn_mfma_f32_16x16x32_bf16(ah[m], bh[n], acc[m][n], 0, 0, 0);
                    if constexpr (SPLIT) {
                        acc[m][n] = __builtin_amdgcn_mfma_f32_16x16x32_bf16(al[m], bh[n], acc[m][n], 0, 0, 0);
                        acc[m][n] = __builtin_amdgcn_mfma_f32_16x16x32_bf16(ah[m], bl[n], acc[m][n], 0, 0, 0);
                    }
                }
        }
        __syncthreads();
    }

    const int r4 = (lane >> 4) << 2;   // C/D: col=lane&15, row=(lane>>4)*4+reg (m89)
#pragma unroll
    for (int n = 0; n < 4; ++n) {
        int colg = bx * 128 + wn * 64 + n * 16 + lrow;
        float bv = bias[colg];
#pragma unroll
        for (int m = 0; m < 4; ++m)
#pragma unroll
            for (int rr = 0; rr < 4; ++rr) {
                int rowg = by * 128 + wm * 64 + m * 16 + r4 + rr;
                float v = acc[m][n][rr] + bv;
                if constexpr (EPI == EPI_F32)
                    ((float*)Cp)[(size_t)rowg * ldc + colg] = v;
                else if constexpr (EPI == EPI_BF16)
                    ((unsigned short*)Cp)[(size_t)rowg * ldc + colg] = f2bf(v);
                else { // EPI_F32T: [b][col][t], b = rowg>>11, t = rowg&2047
                    ((float*)Cp)[(size_t)(rowg >> 11) * 2097152 +
                                 (size_t)colg * 2048 + (rowg & 2047)] = v;
                }
            }
    }
}

// ---------------- FFT autocorrelation ----------------
// Per block: 16 channels of one batch. z[t] = q_c[t] + i*k_c[t]; radix-2 DIF
// FFT (output bit-reversed); Hermitian unpack Qhat/Khat; accumulate
// P[f] = Qhat*conj(Khat) into sacc; atomicAdd into S[b][f] (f = 0..1024).
__global__ __launch_bounds__(256) void fftcorr_k(const float* __restrict__ QT,
                                                 const float* __restrict__ KT,
                                                 float* __restrict__ S)
{
    __shared__ float2 z[2048];
    __shared__ float2 tw[1024];
    __shared__ float2 sacc[1025];
    const int tid = threadIdx.x;
    const int cg = blockIdx.x, b = blockIdx.y;

    for (int j = tid; j < 1024; j += 256) {
        float a = (float)j * (1.0f / 1024.0f);      // w_N^j = e^{-i*pi*a}
        tw[j] = make_float2(cospif(a), -sinpif(a));
    }
    for (int j = tid; j < 1025; j += 256) sacc[j] = make_float2(0.f, 0.f);
    __syncthreads();

    const float* Qb = QT + (size_t)b * 2097152 + (size_t)cg * 16 * 2048;
    const float* Kb = KT + (size_t)b * 2097152 + (size_t)cg * 16 * 2048;

    for (int c = 0; c < 16; ++c) {
#pragma unroll
        for (int j = 0; j < 2; ++j) {
            int t4 = j * 256 + tid;
            f32x4 q = *(const f32x4*)(Qb + (size_t)c * 2048 + t4 * 4);
            f32x4 k = *(const f32x4*)(Kb + (size_t)c * 2048 + t4 * 4);
#pragma unroll
            for (int i = 0; i < 4; ++i) z[t4 * 4 + i] = make_float2(q[i], k[i]);
        }
        __syncthreads();

        for (int s = 0; s < 11; ++s) {
            const int half = 1024 >> s;
#pragma unroll
            for (int r = 0; r < 4; ++r) {
                int i = r * 256 + tid;
                int pos = i & (half - 1);
                int top = ((i >> (10 - s)) << (11 - s)) + pos;
                int bot = top + half;
                float2 a = z[top], bb = z[bot];
                z[top] = make_float2(a.x + bb.x, a.y + bb.y);
                float dx = a.x - bb.x, dy = a.y - bb.y;
                float2 w = tw[pos << s];
                z[bot] = make_float2(dx * w.x - dy * w.y, dx * w.y + dy * w.x);
            }
            __syncthreads();
        }

        for (int f = tid; f <= 1024; f += 256) {
            int rf = __brev((unsigned)f) >> 21;
            int rn = __brev((unsigned)((2048 - f) & 2047)) >> 21;
            float2 Zf = z[rf], Zn = z[rn];
            float qr = 0.5f * (Zf.x + Zn.x), qi = 0.5f * (Zf.y - Zn.y);
            float kr = 0.5f * (Zf.y + Zn.y), ki = 0.5f * (Zn.x - Zf.x);
            sacc[f].x += qr * kr + qi * ki;
            sacc[f].y += qi * kr - qr * ki;
        }
        __syncthreads();
    }
    for (int f = tid; f <= 1024; f += 256) {
        atomicAdd(&S[(size_t)(b * 1025 + f) * 2], sacc[f].x);
        atomicAdd(&S[(size_t)(b * 1025 + f) * 2 + 1], sacc[f].y);
    }
}

// Inverse: mean_value[b,tau] = Re{ (1/2048) sum_f X[f] e^{+i 2pi f tau/2048} } / 1024
// via conj -> forward DIF FFT -> conj; X Hermitian-extended from S.
__global__ __launch_bounds__(256) void icorr_k(const float* __restrict__ S,
                                               float* __restrict__ mv)
{
    __shared__ float2 z[2048];
    __shared__ float2 tw[1024];
    const int tid = threadIdx.x, b = blockIdx.x;
    for (int j = tid; j < 1024; j += 256) {
        float a = (float)j * (1.0f / 1024.0f);
        tw[j] = make_float2(cospif(a), -sinpif(a));
    }
    __syncthreads();
    for (int f = tid; f <= 1024; f += 256) {
        float re = S[(size_t)(b * 1025 + f) * 2];
        float im = S[(size_t)(b * 1025 + f) * 2 + 1];
        z[f] = make_float2(re, -im);                       // conj(X[f])
        if (f >= 1 && f <= 1023) z[2048 - f] = make_float2(re, im); // conj(conj(S[f]))
    }
    __syncthreads();
    for (int s = 0; s < 11; ++s) {
        const int half = 1024 >> s;
#pragma unroll
        for (int r = 0; r < 4; ++r) {
            int i = r * 256 + tid;
            int pos = i & (half - 1);
            int top = ((i >> (10 - s)) << (11 - s)) + pos;
            int bot = top + half;
            float2 a = z[top], bb = z[bot];
            z[top] = make_float2(a.x + bb.x, a.y + bb.y);
            float dx = a.x - bb.x, dy = a.y - bb.y;
            float2 w = tw[pos << s];
            z[bot] = make_float2(dx * w.x - dy * w.y, dx * w.y + dy * w.x);
        }
        __syncthreads();
    }
    for (int t = tid; t < 2048; t += 256) {
        mv[b * 2048 + t] = z[__brev((unsigned)t) >> 21].x * (1.0f / (2048.0f * 1024.0f));
    }
}

// Stable top-7 (lax.top_k semantics) + softmax.
__global__ __launch_bounds__(256) void topk_k(const float* __restrict__ mv,
                                              float* __restrict__ wts,
                                              int* __restrict__ dly)
{
    const int b = blockIdx.x, t = threadIdx.x;
    __shared__ float v[2048];
    __shared__ float rv[256];
    __shared__ int   ri[256];
    __shared__ float topv[7];
    __shared__ int   topi[7];
    for (int i = t; i < 2048; i += 256) v[i] = mv[b * 2048 + i];
    __syncthreads();
    for (int k = 0; k < 7; ++k) {
        float bvv = -INFINITY; int bii = 0x7fffffff;
        for (int i = t; i < 2048; i += 256) {
            float x = v[i];
            if (x > bvv) { bvv = x; bii = i; }
        }
        rv[t] = bvv; ri[t] = bii;
        __syncthreads();
        for (int s = 128; s > 0; s >>= 1) {
            if (t < s) {
                float ov = rv[t + s]; int oi = ri[t + s];
                if (ov > rv[t] || (ov == rv[t] && oi < ri[t])) { rv[t] = ov; ri[t] = oi; }
            }
            __syncthreads();
        }
        if (t == 0) { topv[k] = rv[0]; topi[k] = ri[0]; v[ri[0]] = -INFINITY; }
        __syncthreads();
    }
    if (t == 0) {
        float mx = topv[0], e[7], s = 0.0f;
        for (int k = 0; k < 7; ++k) { e[k] = expf(topv[k] - mx); s += e[k]; }
        for (int k = 0; k < 7; ++k) { wts[b * 7 + k] = e[k] / s; dly[b * 7 + k] = topi[k]; }
    }
}

// V_agg[b,t,:] = sum_k w_k * V[b,(t+d_k)%2048,:]  (bf16 in/out)
__global__ __launch_bounds__(256) void gather_k(const unsigned short* __restrict__ V,
                                                const float* __restrict__ wts,
                                                const int* __restrict__ dly,
                                                unsigned short* __restrict__ Vagg)
{
    int idx = blockIdx.x * 256 + threadIdx.x;
    int c   = (idx & 127) << 3;
    int row = idx >> 7;
    int b = row >> 11, t = row & 2047;
    float acc[8] = {0.f, 0.f, 0.f, 0.f, 0.f, 0.f, 0.f, 0.f};
    for (int k = 0; k < 7; ++k) {
        float w = wts[b * 7 + k];
        int   d = dly[b * 7 + k];
        const unsigned short* s = V + (((size_t)((b << 11) + ((t + d) & 2047))) << 10) + c;
        u16x8 x = *(const u16x8*)s;
#pragma unroll
        for (int j = 0; j < 8; ++j) acc[j] += w * bf2f(x[j]);
    }
    u16x8 o;
#pragma unroll
    for (int j = 0; j < 8; ++j) o[j] = f2bf(acc[j]);
    *(u16x8*)(Vagg + (((size_t)row) << 10) + c) = o;
}

extern "C" void kernel_launch(void* const* d_in, const int* in_sizes, int n_in,
                              void* d_out, int out_size, void* d_ws, size_t ws_size,
                              hipStream_t stream) {
    const float* q_in = (const float*)d_in[0];
    const float* k_in = (const float*)d_in[1];
    const float* v_in = (const float*)d_in[2];
    const float* Wq   = (const float*)d_in[3];
    const float* bq   = (const float*)d_in[4];
    const float* Wk   = (const float*)d_in[5];
    const float* bk   = (const float*)d_in[6];
    const float* Wv   = (const float*)d_in[7];
    const float* bv   = (const float*)d_in[8];
    const float* Wo   = (const float*)d_in[9];
    const float* bo   = (const float*)d_in[10];

    // QT (fp32 transposed, 64 MiB) lives in d_out: dead before the final GEMM.
    float* QT = (float*)d_out;
    char*  ws = (char*)d_ws;
    float*          KT   = (float*)(ws);                        // 67108864 B
    unsigned short* Vbf  = (unsigned short*)(ws + 67108864);    // 33554432 B
    unsigned short* Vagg = (unsigned short*)(ws + 100663296);   // 33554432 B
    float*          mv   = (float*)(ws + 134217728);            // 65536 B
    float*          S    = (float*)(ws + 134283264);            // 65600 B
    float*          wts  = (float*)(ws + 134349056);
    int*            dly  = (int*)(ws + 134349312);

    hipMemsetAsync(S, 0, 8 * 1025 * 2 * sizeof(float), stream);

    dim3 blk(256, 1, 1);
    dim3 gproj(8, 128, 1);

    // QT = (q_in @ Wq^T + bq)^T per batch   (split-3, fp32 transposed out)
    gemm_k<1, 0, EPI_F32T><<<gproj, blk, 0, stream>>>(q_in, Wq, bq, QT,
        1024, 1024, 1024, 1024);
    // KT = (k_in @ Wk^T + bk)^T per batch
    gemm_k<1, 0, EPI_F32T><<<gproj, blk, 0, stream>>>(k_in, Wk, bk, KT,
        1024, 1024, 1024, 1024);
    // V = v_in @ Wv^T + bv   (1-pass, bf16 out)
    gemm_k<0, 0, EPI_BF16><<<gproj, blk, 0, stream>>>(v_in, Wv, bv, Vbf,
        1024, 1024, 1024, 1024);
    // S[b,f] = sum_c Qhat_c[f] * conj(Khat_c[f])
    fftcorr_k<<<dim3(64, 8, 1), blk, 0, stream>>>(QT, KT, S);
    // mean_value = irfft(S)/1024
    icorr_k<<<dim3(8, 1, 1), blk, 0, stream>>>(S, mv);
    // top-7 + softmax
    topk_k<<<dim3(8, 1, 1), blk, 0, stream>>>(mv, wts, dly);
    // weighted circular gather
    gather_k<<<dim3(8192, 1, 1), blk, 0, stream>>>(Vbf, wts, dly, Vagg);
    // out = V_agg @ Wo^T + bo   (1-pass, A bf16, fp32 out -> overwrites QT)
    gemm_k<0, 1, EPI_F32><<<gproj, blk, 0, stream>>>(Vagg, Wo, bo, (float*)d_out,
        1024, 1024, 1024, 1024);
}